// Round 6
// baseline (582.196 us; speedup 1.0000x reference)
//
#include <hip/hip_runtime.h>
#include <hip/hip_bf16.h>

#define N_NODES 50000
#define N_EDGES 800000
#define NBUK 512            // col-range buckets
#define BWID 98             // cols per bucket: 512*98 = 50176 >= N
#define BCAP 2048           // entries cap/bucket (mean 1568, +12 sigma)
#define PCHUNK 8192         // edges per partition block
#define PBLK 98             // ceil(800000/8192)

typedef __bf16 bf16x8 __attribute__((ext_vector_type(8)));
typedef float f32x4 __attribute__((ext_vector_type(4)));

__device__ __forceinline__ unsigned short f2bf(float f) {
    unsigned int u = __builtin_bit_cast(unsigned int, f);
    u += 0x7fffu + ((u >> 16) & 1u);   // round-to-nearest-even
    return (unsigned short)(u >> 16);
}

// ---------------- Wvbar prep: head-averaged Wv -> bf16 [64][256]; bvbar[64] ----
__global__ __launch_bounds__(256) void k_wprep(const float* __restrict__ Wv,
                                               const float* __restrict__ bv,
                                               unsigned short* __restrict__ wvbar,
                                               float* __restrict__ bvbar) {
    int idx = blockIdx.x * 256 + threadIdx.x;   // 16 blocks -> 4096, 4 cols each
    int d = idx >> 6;
    int c = (idx & 63) * 4;
    const float4* W4 = (const float4*)Wv;
    float4 w0 = W4[((d) * 256 + c) >> 2];
    float4 w1 = W4[((64 + d) * 256 + c) >> 2];
    float4 w2 = W4[((128 + d) * 256 + c) >> 2];
    float4 w3 = W4[((192 + d) * 256 + c) >> 2];
    ushort4 s;
    s.x = f2bf(0.25f * (w0.x + w1.x + w2.x + w3.x));
    s.y = f2bf(0.25f * (w0.y + w1.y + w2.y + w3.y));
    s.z = f2bf(0.25f * (w0.z + w1.z + w2.z + w3.z));
    s.w = f2bf(0.25f * (w0.w + w1.w + w2.w + w3.w));
    *(ushort4*)&wvbar[idx * 4] = s;
    if (blockIdx.x == 0 && threadIdx.x < 64) {
        int t = threadIdx.x;
        bvbar[t] = 0.25f * (bv[t] + bv[64 + t] + bv[128 + t] + bv[192 + t]);
    }
}

// ---------------- vbar GEMM (64-row tiles, full-K, single stage) ----------------
// vbar[n,d] = sum_c Xs[n,c]*Wvbar[d,c] + bvbar[d]; vsumcol[d] += sum_n acc (pre-bias)
__global__ __launch_bounds__(256, 2) void k_vbar(
    const float* __restrict__ Xs, const unsigned short* __restrict__ wvbar,
    const float* __restrict__ bvbar, float* __restrict__ vbar,
    float* __restrict__ vsumcol)
{
    __shared__ unsigned short lA[64 * 264];   // 64 rows x 256 k, stride 264 (pad)
    __shared__ unsigned short lB[64 * 264];   // 64 d-rows x 256 k, stride 264 (pad)
    __shared__ float lvs[64];
    const int t = threadIdx.x;
    const int n0 = blockIdx.x * 64;
    const int w = t >> 6;
    const int ln = t & 15;
    const int q = (t & 63) >> 4;

    if (t < 64) lvs[t] = 0.f;

    // --- B: load precomputed Wvbar bf16 (L2-hot), 8 x uint4 per thread ---
    {
        const uint4* Wb = (const uint4*)wvbar;
        #pragma unroll
        for (int j = 0; j < 8; ++j) {
            int g = j * 256 + t;              // uint4 index: d = g>>5, cblk = g&31
            uint4 u = Wb[g];
            *(uint4*)&lB[(g >> 5) * 264 + (g & 31) * 8] = u;
        }
    }

    // --- A: stage 64 rows x 256 cols fp32 -> bf16, 16 float4 per thread ---
    {
        const int r = t >> 2;                 // row within tile
        const int cblk = (t & 3) * 16;        // float4 block base
        const int g = n0 + r;
        const float4* X4 = (const float4*)Xs;
        if (g < N_NODES) {
            #pragma unroll
            for (int i = 0; i < 16; ++i) {
                float4 x = X4[g * 64 + cblk + i];
                ushort4 s;
                s.x = f2bf(x.x); s.y = f2bf(x.y); s.z = f2bf(x.z); s.w = f2bf(x.w);
                *(ushort4*)&lA[r * 264 + (cblk + i) * 4] = s;
            }
        } else {
            #pragma unroll
            for (int i = 0; i < 16; ++i)
                *(ushort4*)&lA[r * 264 + (cblk + i) * 4] = (ushort4){0, 0, 0, 0};
        }
    }
    __syncthreads();

    f32x4 acc[4];
    #pragma unroll
    for (int nf = 0; nf < 4; ++nf) acc[nf] = (f32x4){0.f, 0.f, 0.f, 0.f};

    #pragma unroll
    for (int ks = 0; ks < 8; ++ks) {
        bf16x8 a = *(const bf16x8*)&lA[(w * 16 + ln) * 264 + ks * 32 + q * 8];
        #pragma unroll
        for (int nf = 0; nf < 4; ++nf) {
            bf16x8 b = *(const bf16x8*)&lB[(nf * 16 + ln) * 264 + ks * 32 + q * 8];
            acc[nf] = __builtin_amdgcn_mfma_f32_16x16x32_bf16(a, b, acc[nf], 0, 0, 0);
        }
    }

    // epilogue: D[m = q*4+r4][n = ln]; write vbar (+bias), reduce column sums
    #pragma unroll
    for (int nf = 0; nf < 4; ++nf) {
        float bvb = bvbar[nf * 16 + ln];
        float p = 0.f;
        #pragma unroll
        for (int r4 = 0; r4 < 4; ++r4) {
            int g = n0 + w * 16 + q * 4 + r4;
            if (g < N_NODES)
                vbar[g * 64 + nf * 16 + ln] = acc[nf][r4] + bvb;
            p += acc[nf][r4];
        }
        atomicAdd(&lvs[nf * 16 + ln], p);
    }
    __syncthreads();
    if (t < 64) atomicAdd(&vsumcol[t], lvs[t]);
}

// ---------------- edge partition into 512 col-range buckets ----------------
// entry = { row<<16 | bf16(w), lcol };  block-contiguous runs per bucket.
__global__ __launch_bounds__(256) void k_part(const int* __restrict__ ei,
                                              const float* __restrict__ ew,
                                              int* __restrict__ gcur,
                                              uint2* __restrict__ bkt)
{
    __shared__ int hist[NBUK];
    __shared__ int cur[NBUK];
    const int t = threadIdx.x;
    const int e0 = blockIdx.x * PCHUNK;
    hist[t] = 0; hist[t + 256] = 0;
    __syncthreads();
    // phase A: histogram cols -> buckets
    #pragma unroll
    for (int k = 0; k < PCHUNK / 256; ++k) {
        int e = e0 + k * 256 + t;
        if (e < N_EDGES) {
            int c = ei[N_EDGES + e];
            atomicAdd(&hist[c / BWID], 1);
        }
    }
    __syncthreads();
    // grab per-bucket base (one global atomic per block-bucket)
    {
        int b = t;
        cur[b] = b * BCAP + atomicAdd(&gcur[b], hist[b]);
        b = t + 256;
        cur[b] = b * BCAP + atomicAdd(&gcur[b], hist[b]);
    }
    __syncthreads();
    // phase B: re-read (L2-hot) and write entries at block-contiguous slots
    #pragma unroll
    for (int k = 0; k < PCHUNK / 256; ++k) {
        int e = e0 + k * 256 + t;
        if (e < N_EDGES) {
            int c = ei[N_EDGES + e];
            int b = c / BWID;
            int row = ei[e];
            float w = ew[e];
            int slot = atomicAdd(&cur[b], 1);
            if (slot < (b + 1) * BCAP) {
                uint2 en;
                en.x = ((unsigned int)row << 16) | (unsigned int)f2bf(w);
                en.y = (unsigned int)(c - b * BWID);
                bkt[slot] = en;
            }
        }
    }
}

// ---------------- per-bucket degree histogram -> deg (contiguous, no atomics) --
__global__ __launch_bounds__(128) void k_degb(const int* __restrict__ gcur,
                                              const uint2* __restrict__ bkt,
                                              int* __restrict__ deg)
{
    __shared__ int hist[BWID];
    const int t = threadIdx.x;
    const int b = blockIdx.x;
    if (t < BWID) hist[t] = 0;
    __syncthreads();
    int cnt = min(gcur[b], BCAP);
    const uint2* base = bkt + b * BCAP;
    for (int i = t; i < cnt; i += 128)
        atomicAdd(&hist[base[i].y], 1);
    __syncthreads();
    if (t < BWID) {
        int col = b * BWID + t;
        if (col < N_NODES) deg[col] = hist[t];
    }
}

// ---------------- bucket gather: LDS accumulate, write-once out ----------------
// out[col,d] = aconst[d] + sum_edges w*rsqrt(deg[row]*deg[col]) * vbar[row,d]
__global__ __launch_bounds__(128) void k_gather2(
    const int* __restrict__ gcur, const uint2* __restrict__ bkt,
    const int* __restrict__ deg, const float* __restrict__ vbar,
    const float* __restrict__ vsumcol, const float* __restrict__ bvbar,
    float* __restrict__ out)
{
    __shared__ float acc[BWID * 64];
    __shared__ float dcol[BWID];
    const int t = threadIdx.x;
    const int b = blockIdx.x;
    const int lane = t & 63;
    const int wv = t >> 6;
    for (int i = t; i < BWID * 64; i += 128) acc[i] = 0.f;
    if (t < BWID) {
        int col = b * BWID + t;
        dcol[t] = (col < N_NODES) ? (float)deg[col] : 0.f;
    }
    __syncthreads();
    int cnt = min(gcur[b], BCAP);
    const uint2* base = bkt + b * BCAP;
    for (int i0 = wv * 4; i0 < cnt; i0 += 8) {
        #pragma unroll
        for (int j = 0; j < 4; ++j) {
            int i = i0 + j;
            if (i < cnt) {
                uint2 en = base[i];
                int row = en.x >> 16;
                float w = __uint_as_float(en.x << 16);
                int lcol = en.y;
                float dr = (float)deg[row];
                float v = vbar[row * 64 + lane];
                float val = (dr > 0.f) ? w * __frsqrt_rn(dr * dcol[lcol]) : 0.f;
                atomicAdd(&acc[lcol * 64 + lane], val * v);
            }
        }
    }
    __syncthreads();
    float aconst = vsumcol[lane] * (1.0f / (float)N_NODES) + bvbar[lane];
    for (int l = wv; l < BWID; l += 2) {
        int col = b * BWID + l;
        if (col < N_NODES) out[col * 64 + lane] = acc[l * 64 + lane] + aconst;
    }
}

extern "C" void kernel_launch(void* const* d_in, const int* in_sizes, int n_in,
                              void* d_out, int out_size, void* d_ws, size_t ws_size,
                              hipStream_t stream)
{
    const float* Xs = (const float*)d_in[1];   // source_input [N,256]
    const float* Wv = (const float*)d_in[6];   // Wv_w [256,256]
    const float* bv = (const float*)d_in[7];   // Wv_b [256]
    const int*   ei = (const int*)d_in[8];     // edge_index [2,E]
    const float* ew = (const float*)d_in[9];   // edge_weight [E]
    float* out = (float*)d_out;                // [N,64]

    float* vbar = (float*)d_ws;                                  // 3,200,000 f (12.8 MB)
    uint2* bkt  = (uint2*)(vbar + (size_t)N_NODES * 64);         // 512*2048 uint2 (8 MB)
    unsigned short* wvbar = (unsigned short*)(bkt + (size_t)NBUK * BCAP); // 16,384 bf16
    float* bvbar   = (float*)(wvbar + 16384);                    // 64
    float* vsumcol = bvbar + 64;                                 // 64
    int*   gcur    = (int*)(vsumcol + 64);                       // 512
    int*   deg     = gcur + NBUK;                                // 50,000

    // zero vsumcol + gcur (adjacent); everything else fully written by kernels
    hipMemsetAsync(vsumcol, 0, (size_t)(64 + NBUK) * 4, stream);
    k_wprep<<<16, 256, 0, stream>>>(Wv, bv, wvbar, bvbar);
    k_vbar<<<(N_NODES + 63) / 64, 256, 0, stream>>>(Xs, wvbar, bvbar, vbar, vsumcol);
    k_part<<<PBLK, 256, 0, stream>>>(ei, ew, gcur, bkt);
    k_degb<<<NBUK, 128, 0, stream>>>(gcur, bkt, deg);
    k_gather2<<<NBUK, 128, 0, stream>>>(gcur, bkt, deg, vbar, vsumcol, bvbar, out);
}

// Round 8
// 234.529 us; speedup vs baseline: 2.4824x; 2.4824x over previous
//
#include <hip/hip_runtime.h>
#include <hip/hip_bf16.h>

#define N_NODES 50000
#define N_EDGES 800000
#define NBUK 512            // col-range buckets
#define BWID 98             // cols per bucket: 512*98 = 50176 >= N
#define BCAP 2048           // entries cap/bucket (mean 1568, +12 sigma)
#define PCHUNK 8192         // edges per partition block
#define PBLK 98             // ceil(800000/8192)

typedef __bf16 bf16x8 __attribute__((ext_vector_type(8)));
typedef float f32x4 __attribute__((ext_vector_type(4)));

__device__ __forceinline__ unsigned short f2bf(float f) {
    unsigned int u = __builtin_bit_cast(unsigned int, f);
    u += 0x7fffu + ((u >> 16) & 1u);   // round-to-nearest-even
    return (unsigned short)(u >> 16);
}

// ---------------- Wvbar prep: head-averaged Wv -> bf16 [64][256]; bvbar[64] ----
__global__ __launch_bounds__(256) void k_wprep(const float* __restrict__ Wv,
                                               const float* __restrict__ bv,
                                               unsigned short* __restrict__ wvbar,
                                               float* __restrict__ bvbar) {
    int idx = blockIdx.x * 256 + threadIdx.x;   // 16 blocks -> 4096, 4 cols each
    int d = idx >> 6;
    int c = (idx & 63) * 4;
    const float4* W4 = (const float4*)Wv;
    float4 w0 = W4[((d) * 256 + c) >> 2];
    float4 w1 = W4[((64 + d) * 256 + c) >> 2];
    float4 w2 = W4[((128 + d) * 256 + c) >> 2];
    float4 w3 = W4[((192 + d) * 256 + c) >> 2];
    ushort4 s;
    s.x = f2bf(0.25f * (w0.x + w1.x + w2.x + w3.x));
    s.y = f2bf(0.25f * (w0.y + w1.y + w2.y + w3.y));
    s.z = f2bf(0.25f * (w0.z + w1.z + w2.z + w3.z));
    s.w = f2bf(0.25f * (w0.w + w1.w + w2.w + w3.w));
    *(ushort4*)&wvbar[idx * 4] = s;
    if (blockIdx.x == 0 && threadIdx.x < 64) {
        int t = threadIdx.x;
        bvbar[t] = 0.25f * (bv[t] + bv[64 + t] + bv[128 + t] + bv[192 + t]);
    }
}

// ---------------- vbar GEMM (64-row tiles, full-K, single stage) ----------------
// vbar[n,d] = sum_c Xs[n,c]*Wvbar[d,c] + bvbar[d]; vsumcol[d] += sum_n acc (pre-bias)
__global__ __launch_bounds__(256, 2) void k_vbar(
    const float* __restrict__ Xs, const unsigned short* __restrict__ wvbar,
    const float* __restrict__ bvbar, float* __restrict__ vbar,
    float* __restrict__ vsumcol)
{
    __shared__ unsigned short lA[64 * 264];   // 64 rows x 256 k, stride 264 (pad)
    __shared__ unsigned short lB[64 * 264];   // 64 d-rows x 256 k, stride 264 (pad)
    __shared__ float lvs[64];
    const int t = threadIdx.x;
    const int n0 = blockIdx.x * 64;
    const int w = t >> 6;
    const int ln = t & 15;
    const int q = (t & 63) >> 4;

    if (t < 64) lvs[t] = 0.f;

    // --- B: load precomputed Wvbar bf16 (L2-hot), 8 x uint4 per thread ---
    {
        const uint4* Wb = (const uint4*)wvbar;
        #pragma unroll
        for (int j = 0; j < 8; ++j) {
            int g = j * 256 + t;              // uint4 index: d = g>>5, cblk = g&31
            uint4 u = Wb[g];
            *(uint4*)&lB[(g >> 5) * 264 + (g & 31) * 8] = u;
        }
    }

    // --- A: stage 64 rows x 256 cols fp32 -> bf16, 16 float4 per thread ---
    {
        const int r = t >> 2;                 // row within tile
        const int cblk = (t & 3) * 16;        // float4 block base
        const int g = n0 + r;
        const float4* X4 = (const float4*)Xs;
        if (g < N_NODES) {
            #pragma unroll
            for (int i = 0; i < 16; ++i) {
                float4 x = X4[g * 64 + cblk + i];
                ushort4 s;
                s.x = f2bf(x.x); s.y = f2bf(x.y); s.z = f2bf(x.z); s.w = f2bf(x.w);
                *(ushort4*)&lA[r * 264 + (cblk + i) * 4] = s;
            }
        } else {
            #pragma unroll
            for (int i = 0; i < 16; ++i)
                *(ushort4*)&lA[r * 264 + (cblk + i) * 4] = (ushort4){0, 0, 0, 0};
        }
    }
    __syncthreads();

    f32x4 acc[4];
    #pragma unroll
    for (int nf = 0; nf < 4; ++nf) acc[nf] = (f32x4){0.f, 0.f, 0.f, 0.f};

    #pragma unroll
    for (int ks = 0; ks < 8; ++ks) {
        bf16x8 a = *(const bf16x8*)&lA[(w * 16 + ln) * 264 + ks * 32 + q * 8];
        #pragma unroll
        for (int nf = 0; nf < 4; ++nf) {
            bf16x8 b = *(const bf16x8*)&lB[(nf * 16 + ln) * 264 + ks * 32 + q * 8];
            acc[nf] = __builtin_amdgcn_mfma_f32_16x16x32_bf16(a, b, acc[nf], 0, 0, 0);
        }
    }

    // epilogue: D[m = q*4+r4][n = ln]; write vbar (+bias), reduce column sums
    #pragma unroll
    for (int nf = 0; nf < 4; ++nf) {
        float bvb = bvbar[nf * 16 + ln];
        float p = 0.f;
        #pragma unroll
        for (int r4 = 0; r4 < 4; ++r4) {
            int g = n0 + w * 16 + q * 4 + r4;
            if (g < N_NODES)
                vbar[g * 64 + nf * 16 + ln] = acc[nf][r4] + bvb;
            p += acc[nf][r4];
        }
        atomicAdd(&lvs[nf * 16 + ln], p);
    }
    __syncthreads();
    if (t < 64) atomicAdd(&vsumcol[t], lvs[t]);
}

// ---------------- edge partition into 512 col-range buckets ----------------
// entry = { row<<16 | bf16(w), lcol };  block-contiguous runs per bucket region.
__global__ __launch_bounds__(256) void k_part(const int* __restrict__ ei,
                                              const float* __restrict__ ew,
                                              int* __restrict__ gcur,
                                              uint2* __restrict__ bkt)
{
    __shared__ int hist[NBUK];
    __shared__ int cur[NBUK];
    const int t = threadIdx.x;
    const int e0 = blockIdx.x * PCHUNK;
    hist[t] = 0; hist[t + 256] = 0;
    __syncthreads();
    // phase A: histogram cols -> buckets
    #pragma unroll
    for (int k = 0; k < PCHUNK / 256; ++k) {
        int e = e0 + k * 256 + t;
        if (e < N_EDGES) {
            int c = ei[N_EDGES + e];
            atomicAdd(&hist[c / BWID], 1);
        }
    }
    __syncthreads();
    // grab per-bucket base (one global atomic per block-bucket)
    {
        int b = t;
        cur[b] = b * BCAP + atomicAdd(&gcur[b], hist[b]);
        b = t + 256;
        cur[b] = b * BCAP + atomicAdd(&gcur[b], hist[b]);
    }
    __syncthreads();
    // phase B: re-read (L2-hot) and write entries at block-contiguous slots
    #pragma unroll
    for (int k = 0; k < PCHUNK / 256; ++k) {
        int e = e0 + k * 256 + t;
        if (e < N_EDGES) {
            int c = ei[N_EDGES + e];
            int b = c / BWID;
            int row = ei[e];
            float w = ew[e];
            int slot = atomicAdd(&cur[b], 1);
            if (slot < (b + 1) * BCAP) {
                uint2 en;
                en.x = ((unsigned int)row << 16) | (unsigned int)f2bf(w);
                en.y = (unsigned int)(c - b * BWID);
                bkt[slot] = en;
            }
        }
    }
}

// ---------------- per-bucket: deg + off (into padded layout) + in-bucket sort --
// All writes stay within this block's own bucket region -> ~1x line writeback.
__global__ __launch_bounds__(256) void k_bucket(const int* __restrict__ gcur,
                                                const uint2* __restrict__ bkt,
                                                int* __restrict__ deg,
                                                int* __restrict__ off,
                                                unsigned int* __restrict__ srt)
{
    __shared__ int hist[128];       // >= BWID
    __shared__ int lcur[128];
    const int t = threadIdx.x;
    const int b = blockIdx.x;
    if (t < 128) hist[t] = 0;
    __syncthreads();
    const int cnt = min(gcur[b], BCAP);
    const uint2* base = bkt + (size_t)b * BCAP;
    for (int i = t; i < cnt; i += 256)
        atomicAdd(&hist[base[i].y], 1);
    __syncthreads();
    // exclusive scan over 128 — ALL threads execute every barrier (t>=128 idle)
    const int v = (t < 128) ? hist[t] : 0;
    #pragma unroll
    for (int d = 1; d < 128; d <<= 1) {
        int u = (t >= d && t < 128) ? hist[t - d] : 0;
        __syncthreads();
        if (t >= d && t < 128) hist[t] += u;
        __syncthreads();
    }
    if (t < 128) {
        int excl = hist[t] - v;     // exclusive prefix
        lcur[t] = excl;
        if (t < BWID) {
            int col = b * BWID + t;
            if (col < N_NODES) {
                deg[col] = v;
                off[col] = b * BCAP + excl;
            }
        }
    }
    __syncthreads();
    // reorder into per-col runs within the bucket region (4 B entries)
    unsigned int* sb = srt + (size_t)b * BCAP;
    for (int i = t; i < cnt; i += 256) {
        uint2 en = base[i];
        int pos = atomicAdd(&lcur[en.y], 1);
        sb[pos] = en.x;             // row<<16 | bf16(w)
    }
}

// ---------------- GCN gather: one wave per node, lane = d-channel ----------------
// out[n,d] = aconst[d] + sum_e w*rsqrt(deg[row]*deg[n]) * vbar[row,d]
__global__ __launch_bounds__(256) void k_gather(
    const int* __restrict__ off, const int* __restrict__ deg,
    const unsigned int* __restrict__ srt, const float* __restrict__ vbar,
    const float* __restrict__ vsumcol, const float* __restrict__ bvbar,
    float* __restrict__ out)
{
    const int t = threadIdx.x;
    const int lane = t & 63;
    const int n = blockIdx.x * 4 + (t >> 6);          // grid: 12544 blocks -> 50176
    if (n >= N_NODES) return;                          // whole wave exits together
    const int e0 = off[n];
    const int dc = deg[n];
    const int e1 = e0 + dc;
    const float dcf = (float)dc;
    float acc = 0.f;
    int e = e0;
    for (; e + 3 < e1; e += 4) {
        unsigned int p0 = srt[e];
        unsigned int p1 = srt[e + 1];
        unsigned int p2 = srt[e + 2];
        unsigned int p3 = srt[e + 3];
        int r0 = p0 >> 16, r1 = p1 >> 16, r2 = p2 >> 16, r3 = p3 >> 16;
        float d0 = (float)deg[r0];
        float d1 = (float)deg[r1];
        float d2 = (float)deg[r2];
        float d3 = (float)deg[r3];
        float w0 = __uint_as_float(p0 << 16);
        float w1 = __uint_as_float(p1 << 16);
        float w2 = __uint_as_float(p2 << 16);
        float w3 = __uint_as_float(p3 << 16);
        float v0 = (d0 > 0.f) ? w0 * __frsqrt_rn(d0 * dcf) : 0.f;
        float v1 = (d1 > 0.f) ? w1 * __frsqrt_rn(d1 * dcf) : 0.f;
        float v2 = (d2 > 0.f) ? w2 * __frsqrt_rn(d2 * dcf) : 0.f;
        float v3 = (d3 > 0.f) ? w3 * __frsqrt_rn(d3 * dcf) : 0.f;
        float a0 = v0 * vbar[r0 * 64 + lane];
        float a1 = v1 * vbar[r1 * 64 + lane];
        float a2 = v2 * vbar[r2 * 64 + lane];
        float a3 = v3 * vbar[r3 * 64 + lane];
        acc += (a0 + a1) + (a2 + a3);
    }
    for (; e < e1; ++e) {
        unsigned int p = srt[e];
        int r = p >> 16;
        float dr = (float)deg[r];
        float w = __uint_as_float(p << 16);
        float val = (dr > 0.f) ? w * __frsqrt_rn(dr * dcf) : 0.f;
        acc += val * vbar[r * 64 + lane];
    }
    float aconst = vsumcol[lane] * (1.0f / (float)N_NODES) + bvbar[lane];
    out[n * 64 + lane] = acc + aconst;
}

extern "C" void kernel_launch(void* const* d_in, const int* in_sizes, int n_in,
                              void* d_out, int out_size, void* d_ws, size_t ws_size,
                              hipStream_t stream)
{
    const float* Xs = (const float*)d_in[1];   // source_input [N,256]
    const float* Wv = (const float*)d_in[6];   // Wv_w [256,256]
    const float* bv = (const float*)d_in[7];   // Wv_b [256]
    const int*   ei = (const int*)d_in[8];     // edge_index [2,E]
    const float* ew = (const float*)d_in[9];   // edge_weight [E]
    float* out = (float*)d_out;                // [N,64]

    float* vbar = (float*)d_ws;                                  // 12.8 MB
    uint2* bkt  = (uint2*)(vbar + (size_t)N_NODES * 64);         // 512*2048*8 = 8.39 MB
    unsigned int* srt = (unsigned int*)(bkt + (size_t)NBUK * BCAP); // 512*2048*4 = 4.19 MB
    unsigned short* wvbar = (unsigned short*)(srt + (size_t)NBUK * BCAP); // 32 KB
    float* bvbar   = (float*)(wvbar + 16384);                    // 64
    float* vsumcol = bvbar + 64;                                 // 64
    int*   gcur    = (int*)(vsumcol + 64);                       // 512
    int*   deg     = gcur + NBUK;                                // 50,000
    int*   off     = deg + N_NODES;                              // 50,000

    // zero vsumcol + gcur (adjacent); everything else fully written by kernels
    hipMemsetAsync(vsumcol, 0, (size_t)(64 + NBUK) * 4, stream);
    k_wprep<<<16, 256, 0, stream>>>(Wv, bv, wvbar, bvbar);
    k_vbar<<<(N_NODES + 63) / 64, 256, 0, stream>>>(Xs, wvbar, bvbar, vbar, vsumcol);
    k_part<<<PBLK, 256, 0, stream>>>(ei, ew, gcur, bkt);
    k_bucket<<<NBUK, 256, 0, stream>>>(gcur, bkt, deg, off, srt);
    k_gather<<<(NBUK * BWID) / 4, 256, 0, stream>>>(off, deg, srt, vbar, vsumcol, bvbar, out);
}

// Round 9
// 226.599 us; speedup vs baseline: 2.5693x; 1.0350x over previous
//
#include <hip/hip_runtime.h>
#include <hip/hip_bf16.h>

#define N_NODES 50000
#define N_EDGES 800000
#define NBUK 512            // col-range buckets
#define BWID 98             // cols per bucket: 512*98 = 50176 >= N
#define BCAP 2048           // entries cap/bucket (mean 1562, +12 sigma)
#define PCHUNK 2048         // edges per partition block
#define PBLK 391            // ceil(800000/2048)

typedef __bf16 bf16x8 __attribute__((ext_vector_type(8)));
typedef float f32x4 __attribute__((ext_vector_type(4)));

__device__ __forceinline__ unsigned short f2bf(float f) {
    unsigned int u = __builtin_bit_cast(unsigned int, f);
    u += 0x7fffu + ((u >> 16) & 1u);   // round-to-nearest-even
    return (unsigned short)(u >> 16);
}

// ---------------- Wvbar prep: head-averaged Wv -> bf16 [64][256]; bvbar[64] ----
__global__ __launch_bounds__(256) void k_wprep(const float* __restrict__ Wv,
                                               const float* __restrict__ bv,
                                               unsigned short* __restrict__ wvbar,
                                               float* __restrict__ bvbar) {
    int idx = blockIdx.x * 256 + threadIdx.x;   // 16 blocks -> 4096, 4 cols each
    int d = idx >> 6;
    int c = (idx & 63) * 4;
    const float4* W4 = (const float4*)Wv;
    float4 w0 = W4[((d) * 256 + c) >> 2];
    float4 w1 = W4[((64 + d) * 256 + c) >> 2];
    float4 w2 = W4[((128 + d) * 256 + c) >> 2];
    float4 w3 = W4[((192 + d) * 256 + c) >> 2];
    ushort4 s;
    s.x = f2bf(0.25f * (w0.x + w1.x + w2.x + w3.x));
    s.y = f2bf(0.25f * (w0.y + w1.y + w2.y + w3.y));
    s.z = f2bf(0.25f * (w0.z + w1.z + w2.z + w3.z));
    s.w = f2bf(0.25f * (w0.w + w1.w + w2.w + w3.w));
    *(ushort4*)&wvbar[idx * 4] = s;
    if (blockIdx.x == 0 && threadIdx.x < 64) {
        int t = threadIdx.x;
        bvbar[t] = 0.25f * (bv[t] + bv[64 + t] + bv[128 + t] + bv[192 + t]);
    }
}

// ---------------- edge partition into 512 col-range buckets ----------------
// entry = { row<<16 | bf16(w), lcol };  block-contiguous runs per bucket region.
__global__ __launch_bounds__(256) void k_part(const int* __restrict__ ei,
                                              const float* __restrict__ ew,
                                              int* __restrict__ gcur,
                                              uint2* __restrict__ bkt)
{
    __shared__ int hist[NBUK];
    __shared__ int cur[NBUK];
    const int t = threadIdx.x;
    const int e0 = blockIdx.x * PCHUNK;
    hist[t] = 0; hist[t + 256] = 0;
    __syncthreads();
    // phase A: histogram cols -> buckets
    #pragma unroll
    for (int k = 0; k < PCHUNK / 256; ++k) {
        int e = e0 + k * 256 + t;
        if (e < N_EDGES) {
            int c = ei[N_EDGES + e];
            atomicAdd(&hist[c / BWID], 1);
        }
    }
    __syncthreads();
    // grab per-bucket base (one global atomic per block-bucket with work)
    {
        int b = t;
        if (hist[b]) cur[b] = b * BCAP + atomicAdd(&gcur[b], hist[b]);
        b = t + 256;
        if (hist[b]) cur[b] = b * BCAP + atomicAdd(&gcur[b], hist[b]);
    }
    __syncthreads();
    // phase B: re-read (L2-hot) and write entries at block-contiguous slots
    #pragma unroll
    for (int k = 0; k < PCHUNK / 256; ++k) {
        int e = e0 + k * 256 + t;
        if (e < N_EDGES) {
            int c = ei[N_EDGES + e];
            int b = c / BWID;
            int row = ei[e];
            float w = ew[e];
            int slot = atomicAdd(&cur[b], 1);
            if (slot < (b + 1) * BCAP) {
                uint2 en;
                en.x = ((unsigned int)row << 16) | (unsigned int)f2bf(w);
                en.y = (unsigned int)(c - b * BWID);
                bkt[slot] = en;
            }
        }
    }
}

// ---------------- per-bucket: deg + off (into padded layout) + in-bucket sort --
// All writes stay within this block's own bucket region -> ~1x line writeback.
__global__ __launch_bounds__(256) void k_bucket(const int* __restrict__ gcur,
                                                const uint2* __restrict__ bkt,
                                                int* __restrict__ deg,
                                                int* __restrict__ off,
                                                unsigned int* __restrict__ srt)
{
    __shared__ int hist[128];       // >= BWID
    __shared__ int lcur[128];
    const int t = threadIdx.x;
    const int b = blockIdx.x;
    if (t < 128) hist[t] = 0;
    __syncthreads();
    const int cnt = min(gcur[b], BCAP);
    const uint2* base = bkt + (size_t)b * BCAP;
    for (int i = t; i < cnt; i += 256)
        atomicAdd(&hist[base[i].y], 1);
    __syncthreads();
    // exclusive scan over 128 — ALL threads execute every barrier (t>=128 idle)
    const int v = (t < 128) ? hist[t] : 0;
    #pragma unroll
    for (int d = 1; d < 128; d <<= 1) {
        int u = (t >= d && t < 128) ? hist[t - d] : 0;
        __syncthreads();
        if (t >= d && t < 128) hist[t] += u;
        __syncthreads();
    }
    if (t < 128) {
        int excl = hist[t] - v;     // exclusive prefix
        lcur[t] = excl;
        if (t < BWID) {
            int col = b * BWID + t;
            if (col < N_NODES) {
                deg[col] = v;
                off[col] = b * BCAP + excl;
            }
        }
    }
    __syncthreads();
    // reorder into per-col runs within the bucket region (4 B entries)
    unsigned int* sb = srt + (size_t)b * BCAP;
    for (int i = t; i < cnt; i += 256) {
        uint2 en = base[i];
        int pos = atomicAdd(&lcur[en.y], 1);
        sb[pos] = en.x;             // row<<16 | bf16(w)
    }
}

// ---------------- vbar GEMM (64-row tiles, full-K, single stage) ----------------
// vbar[n,d] = (sum_c Xs[n,c]*Wvbar[d,c] + bvbar[d]) * rsqrt(deg[n])  (0 if deg=0)
// vsumcol[d] += sum_n acc (pre-bias, UNSCALED) for the attention constant.
__global__ __launch_bounds__(256, 2) void k_vbar(
    const float* __restrict__ Xs, const unsigned short* __restrict__ wvbar,
    const float* __restrict__ bvbar, const int* __restrict__ deg,
    float* __restrict__ vbar, float* __restrict__ vsumcol)
{
    __shared__ unsigned short lA[64 * 264];   // 64 rows x 256 k, stride 264 (pad)
    __shared__ unsigned short lB[64 * 264];   // 64 d-rows x 256 k, stride 264 (pad)
    __shared__ float lvs[64];
    const int t = threadIdx.x;
    const int n0 = blockIdx.x * 64;
    const int w = t >> 6;
    const int ln = t & 15;
    const int q = (t & 63) >> 4;

    if (t < 64) lvs[t] = 0.f;

    // --- B: load precomputed Wvbar bf16 (L2-hot), 8 x uint4 per thread ---
    {
        const uint4* Wb = (const uint4*)wvbar;
        #pragma unroll
        for (int j = 0; j < 8; ++j) {
            int g = j * 256 + t;              // uint4 index: d = g>>5, cblk = g&31
            uint4 u = Wb[g];
            *(uint4*)&lB[(g >> 5) * 264 + (g & 31) * 8] = u;
        }
    }

    // --- A: stage 64 rows x 256 cols fp32 -> bf16, 16 float4 per thread ---
    {
        const int r = t >> 2;                 // row within tile
        const int cblk = (t & 3) * 16;        // float4 block base
        const int g = n0 + r;
        const float4* X4 = (const float4*)Xs;
        if (g < N_NODES) {
            #pragma unroll
            for (int i = 0; i < 16; ++i) {
                float4 x = X4[g * 64 + cblk + i];
                ushort4 s;
                s.x = f2bf(x.x); s.y = f2bf(x.y); s.z = f2bf(x.z); s.w = f2bf(x.w);
                *(ushort4*)&lA[r * 264 + (cblk + i) * 4] = s;
            }
        } else {
            #pragma unroll
            for (int i = 0; i < 16; ++i)
                *(ushort4*)&lA[r * 264 + (cblk + i) * 4] = (ushort4){0, 0, 0, 0};
        }
    }
    __syncthreads();

    f32x4 acc[4];
    #pragma unroll
    for (int nf = 0; nf < 4; ++nf) acc[nf] = (f32x4){0.f, 0.f, 0.f, 0.f};

    #pragma unroll
    for (int ks = 0; ks < 8; ++ks) {
        bf16x8 a = *(const bf16x8*)&lA[(w * 16 + ln) * 264 + ks * 32 + q * 8];
        #pragma unroll
        for (int nf = 0; nf < 4; ++nf) {
            bf16x8 b = *(const bf16x8*)&lB[(nf * 16 + ln) * 264 + ks * 32 + q * 8];
            acc[nf] = __builtin_amdgcn_mfma_f32_16x16x32_bf16(a, b, acc[nf], 0, 0, 0);
        }
    }

    // epilogue: D[m = q*4+r4][n = ln]; write vbar pre-scaled by rsqrt(deg[row])
    float bvb[4];
    #pragma unroll
    for (int nf = 0; nf < 4; ++nf) bvb[nf] = bvbar[nf * 16 + ln];
    float psum[4] = {0.f, 0.f, 0.f, 0.f};
    #pragma unroll
    for (int r4 = 0; r4 < 4; ++r4) {
        int g = n0 + w * 16 + q * 4 + r4;
        bool ok = g < N_NODES;
        float sc = 0.f;
        if (ok) {
            float dg = (float)deg[g];
            sc = (dg > 0.f) ? __frsqrt_rn(dg) : 0.f;
        }
        #pragma unroll
        for (int nf = 0; nf < 4; ++nf) {
            if (ok) vbar[g * 64 + nf * 16 + ln] = (acc[nf][r4] + bvb[nf]) * sc;
            psum[nf] += acc[nf][r4];
        }
    }
    #pragma unroll
    for (int nf = 0; nf < 4; ++nf) atomicAdd(&lvs[nf * 16 + ln], psum[nf]);
    __syncthreads();
    if (t < 64) atomicAdd(&vsumcol[t], lvs[t]);
}

// ---------------- GCN gather: one wave per node, lane = d-channel ----------------
// out[n,d] = aconst[d] + rsqrt(deg[n]) * sum_e w_e * vbar[row_e, d]   (vbar pre-scaled)
__global__ __launch_bounds__(256) void k_gather(
    const int* __restrict__ off, const int* __restrict__ deg,
    const unsigned int* __restrict__ srt, const float* __restrict__ vbar,
    const float* __restrict__ vsumcol, const float* __restrict__ bvbar,
    float* __restrict__ out)
{
    const int t = threadIdx.x;
    const int lane = t & 63;
    const int n = blockIdx.x * 4 + (t >> 6);          // grid: 12544 blocks -> 50176
    if (n >= N_NODES) return;                          // whole wave exits together
    const int e0 = off[n];
    const int dc = deg[n];
    const int e1 = e0 + dc;
    float acc = 0.f;
    int e = e0;
    for (; e + 3 < e1; e += 4) {
        unsigned int p0 = srt[e];
        unsigned int p1 = srt[e + 1];
        unsigned int p2 = srt[e + 2];
        unsigned int p3 = srt[e + 3];
        float a0 = __uint_as_float(p0 << 16) * vbar[(p0 >> 16) * 64 + lane];
        float a1 = __uint_as_float(p1 << 16) * vbar[(p1 >> 16) * 64 + lane];
        float a2 = __uint_as_float(p2 << 16) * vbar[(p2 >> 16) * 64 + lane];
        float a3 = __uint_as_float(p3 << 16) * vbar[(p3 >> 16) * 64 + lane];
        acc += (a0 + a1) + (a2 + a3);
    }
    for (; e < e1; ++e) {
        unsigned int p = srt[e];
        acc += __uint_as_float(p << 16) * vbar[(p >> 16) * 64 + lane];
    }
    float dcf = (float)dc;
    float scn = (dcf > 0.f) ? __frsqrt_rn(dcf) : 0.f;
    float aconst = vsumcol[lane] * (1.0f / (float)N_NODES) + bvbar[lane];
    out[n * 64 + lane] = acc * scn + aconst;
}

extern "C" void kernel_launch(void* const* d_in, const int* in_sizes, int n_in,
                              void* d_out, int out_size, void* d_ws, size_t ws_size,
                              hipStream_t stream)
{
    const float* Xs = (const float*)d_in[1];   // source_input [N,256]
    const float* Wv = (const float*)d_in[6];   // Wv_w [256,256]
    const float* bv = (const float*)d_in[7];   // Wv_b [256]
    const int*   ei = (const int*)d_in[8];     // edge_index [2,E]
    const float* ew = (const float*)d_in[9];   // edge_weight [E]
    float* out = (float*)d_out;                // [N,64]

    float* vbar = (float*)d_ws;                                  // 12.8 MB
    uint2* bkt  = (uint2*)(vbar + (size_t)N_NODES * 64);         // 512*2048*8 = 8.39 MB
    unsigned int* srt = (unsigned int*)(bkt + (size_t)NBUK * BCAP); // 512*2048*4 = 4.19 MB
    unsigned short* wvbar = (unsigned short*)(srt + (size_t)NBUK * BCAP); // 32 KB
    float* bvbar   = (float*)(wvbar + 16384);                    // 64
    float* vsumcol = bvbar + 64;                                 // 64
    int*   gcur    = (int*)(vsumcol + 64);                       // 512
    int*   deg     = gcur + NBUK;                                // 50,000
    int*   off     = deg + N_NODES;                              // 50,000

    // zero vsumcol + gcur (adjacent); everything else fully written by kernels
    hipMemsetAsync(vsumcol, 0, (size_t)(64 + NBUK) * 4, stream);
    k_wprep<<<16, 256, 0, stream>>>(Wv, bv, wvbar, bvbar);
    k_part<<<PBLK, 256, 0, stream>>>(ei, ew, gcur, bkt);
    k_bucket<<<NBUK, 256, 0, stream>>>(gcur, bkt, deg, off, srt);
    k_vbar<<<(N_NODES + 63) / 64, 256, 0, stream>>>(Xs, wvbar, bvbar, deg, vbar, vsumcol);
    k_gather<<<(NBUK * BWID) / 4, 256, 0, stream>>>(off, deg, srt, vbar, vsumcol, bvbar, out);
}

// Round 10
// 221.791 us; speedup vs baseline: 2.6250x; 1.0217x over previous
//
#include <hip/hip_runtime.h>
#include <hip/hip_bf16.h>

#define N_NODES 50000
#define N_EDGES 800000
#define NBUK 512            // col-range buckets
#define BWID 98             // cols per bucket: 512*98 = 50176 >= N
#define BCAP 2048           // entries cap/bucket (mean 1562, +12 sigma)
#define PCHUNK 2048         // edges per partition block
#define PBLK 391            // ceil(800000/2048)

typedef __bf16 bf16x8 __attribute__((ext_vector_type(8)));
typedef float f32x4 __attribute__((ext_vector_type(4)));

__device__ __forceinline__ unsigned short f2bf(float f) {
    unsigned int u = __builtin_bit_cast(unsigned int, f);
    u += 0x7fffu + ((u >> 16) & 1u);   // round-to-nearest-even
    return (unsigned short)(u >> 16);
}
__device__ __forceinline__ float bf2f(unsigned short s) {
    return __uint_as_float((unsigned int)s << 16);
}

// ---------------- Wvbar prep: head-averaged Wv -> bf16, MFMA-frag-swizzled ----
// element (d,c) -> frag ks=c>>5, nf=d>>4, lane = ((c>>3)&3)*16 + (d&15), j=c&7
// stored at ((ks*4+nf)*64 + lane)*8 + j  (so a wave's b-frag load is 1 KB coalesced)
__global__ __launch_bounds__(256) void k_wprep(const float* __restrict__ Wv,
                                               const float* __restrict__ bv,
                                               unsigned short* __restrict__ wvbar,
                                               float* __restrict__ bvbar) {
    int idx = blockIdx.x * 256 + threadIdx.x;   // 16 blocks -> 4096, 4 cols each
    int d = idx >> 6;
    int c0 = (idx & 63) * 4;
    const float4* W4 = (const float4*)Wv;
    float4 w0 = W4[((d) * 256 + c0) >> 2];
    float4 w1 = W4[((64 + d) * 256 + c0) >> 2];
    float4 w2 = W4[((128 + d) * 256 + c0) >> 2];
    float4 w3 = W4[((192 + d) * 256 + c0) >> 2];
    ushort4 s;
    s.x = f2bf(0.25f * (w0.x + w1.x + w2.x + w3.x));
    s.y = f2bf(0.25f * (w0.y + w1.y + w2.y + w3.y));
    s.z = f2bf(0.25f * (w0.z + w1.z + w2.z + w3.z));
    s.w = f2bf(0.25f * (w0.w + w1.w + w2.w + w3.w));
    int ks = c0 >> 5;
    int q  = (c0 >> 3) & 3;
    int j0 = c0 & 7;                            // 0 or 4 -> ushort4 stays contiguous
    int nf = d >> 4;
    int ln = d & 15;
    int base = ((ks * 4 + nf) * 64 + q * 16 + ln) * 8 + j0;
    *(ushort4*)&wvbar[base] = s;
    if (blockIdx.x == 0 && threadIdx.x < 64) {
        int t = threadIdx.x;
        bvbar[t] = 0.25f * (bv[t] + bv[64 + t] + bv[128 + t] + bv[192 + t]);
    }
}

// ---------------- edge partition into 512 col-range buckets ----------------
// entry = { row<<16 | bf16(w), lcol };  block-contiguous runs per bucket region.
__global__ __launch_bounds__(256) void k_part(const int* __restrict__ ei,
                                              const float* __restrict__ ew,
                                              int* __restrict__ gcur,
                                              uint2* __restrict__ bkt)
{
    __shared__ int hist[NBUK];
    __shared__ int cur[NBUK];
    const int t = threadIdx.x;
    const int e0 = blockIdx.x * PCHUNK;
    hist[t] = 0; hist[t + 256] = 0;
    __syncthreads();
    #pragma unroll
    for (int k = 0; k < PCHUNK / 256; ++k) {
        int e = e0 + k * 256 + t;
        if (e < N_EDGES) {
            int c = ei[N_EDGES + e];
            atomicAdd(&hist[c / BWID], 1);
        }
    }
    __syncthreads();
    {
        int b = t;
        if (hist[b]) cur[b] = b * BCAP + atomicAdd(&gcur[b], hist[b]);
        b = t + 256;
        if (hist[b]) cur[b] = b * BCAP + atomicAdd(&gcur[b], hist[b]);
    }
    __syncthreads();
    #pragma unroll
    for (int k = 0; k < PCHUNK / 256; ++k) {
        int e = e0 + k * 256 + t;
        if (e < N_EDGES) {
            int c = ei[N_EDGES + e];
            int b = c / BWID;
            int row = ei[e];
            float w = ew[e];
            int slot = atomicAdd(&cur[b], 1);
            if (slot < (b + 1) * BCAP) {
                uint2 en;
                en.x = ((unsigned int)row << 16) | (unsigned int)f2bf(w);
                en.y = (unsigned int)(c - b * BWID);
                bkt[slot] = en;
            }
        }
    }
}

// ---------------- per-bucket: deg + off (into padded layout) + in-bucket sort --
__global__ __launch_bounds__(256) void k_bucket(const int* __restrict__ gcur,
                                                const uint2* __restrict__ bkt,
                                                int* __restrict__ deg,
                                                int* __restrict__ off,
                                                unsigned int* __restrict__ srt)
{
    __shared__ int hist[128];       // >= BWID
    __shared__ int lcur[128];
    const int t = threadIdx.x;
    const int b = blockIdx.x;
    if (t < 128) hist[t] = 0;
    __syncthreads();
    const int cnt = min(gcur[b], BCAP);
    const uint2* base = bkt + (size_t)b * BCAP;
    for (int i = t; i < cnt; i += 256)
        atomicAdd(&hist[base[i].y], 1);
    __syncthreads();
    // exclusive scan over 128 — ALL threads execute every barrier (t>=128 idle)
    const int v = (t < 128) ? hist[t] : 0;
    #pragma unroll
    for (int d = 1; d < 128; d <<= 1) {
        int u = (t >= d && t < 128) ? hist[t - d] : 0;
        __syncthreads();
        if (t >= d && t < 128) hist[t] += u;
        __syncthreads();
    }
    if (t < 128) {
        int excl = hist[t] - v;
        lcur[t] = excl;
        if (t < BWID) {
            int col = b * BWID + t;
            if (col < N_NODES) {
                deg[col] = v;
                off[col] = b * BCAP + excl;
            }
        }
    }
    __syncthreads();
    unsigned int* sb = srt + (size_t)b * BCAP;
    for (int i = t; i < cnt; i += 256) {
        uint2 en = base[i];
        int pos = atomicAdd(&lcur[en.y], 1);
        sb[pos] = en.x;             // row<<16 | bf16(w)
    }
}

// ---------------- vbar GEMM (64-row tiles, full-K, B direct from global) -------
// vbarh[n,d] = bf16( (sum_c Xs[n,c]*Wvbar[d,c] + bvbar[d]) * rsqrt(deg[n]) )
// vsumcol[d] += sum_n acc (pre-bias, UNSCALED) for the attention constant.
__global__ __launch_bounds__(256, 4) void k_vbar(
    const float* __restrict__ Xs, const unsigned short* __restrict__ wvbar,
    const float* __restrict__ bvbar, const int* __restrict__ deg,
    unsigned short* __restrict__ vbarh, float* __restrict__ vsumcol)
{
    __shared__ unsigned short lA[64 * 264];   // 64 rows x 256 k, stride 264 (pad)
    __shared__ float lvs[64];
    const int t = threadIdx.x;
    const int n0 = blockIdx.x * 64;
    const int w = t >> 6;
    const int l = t & 63;
    const int ln = l & 15;
    const int q = l >> 4;

    if (t < 64) lvs[t] = 0.f;

    // --- A: stage 64 rows x 256 cols fp32 -> bf16, 16 float4 per thread ---
    {
        const int r = t >> 2;                 // row within tile
        const int cblk = (t & 3) * 16;        // float4 block base
        const int g = n0 + r;
        const float4* X4 = (const float4*)Xs;
        if (g < N_NODES) {
            #pragma unroll
            for (int i = 0; i < 16; ++i) {
                float4 x = X4[g * 64 + cblk + i];
                ushort4 s;
                s.x = f2bf(x.x); s.y = f2bf(x.y); s.z = f2bf(x.z); s.w = f2bf(x.w);
                *(ushort4*)&lA[r * 264 + (cblk + i) * 4] = s;
            }
        } else {
            #pragma unroll
            for (int i = 0; i < 16; ++i)
                *(ushort4*)&lA[r * 264 + (cblk + i) * 4] = (ushort4){0, 0, 0, 0};
        }
    }
    __syncthreads();

    f32x4 acc[4];
    #pragma unroll
    for (int nf = 0; nf < 4; ++nf) acc[nf] = (f32x4){0.f, 0.f, 0.f, 0.f};

    const bf16x8* Wf = (const bf16x8*)wvbar;   // frag-swizzled, L2-hot
    #pragma unroll
    for (int ks = 0; ks < 8; ++ks) {
        bf16x8 a = *(const bf16x8*)&lA[(w * 16 + ln) * 264 + ks * 32 + q * 8];
        #pragma unroll
        for (int nf = 0; nf < 4; ++nf) {
            bf16x8 b = Wf[(ks * 4 + nf) * 64 + l];
            acc[nf] = __builtin_amdgcn_mfma_f32_16x16x32_bf16(a, b, acc[nf], 0, 0, 0);
        }
    }

    // epilogue: D[m = q*4+r4][n = ln]; write bf16 vbar pre-scaled by rsqrt(deg)
    float bvb[4];
    #pragma unroll
    for (int nf = 0; nf < 4; ++nf) bvb[nf] = bvbar[nf * 16 + ln];
    float psum[4] = {0.f, 0.f, 0.f, 0.f};
    #pragma unroll
    for (int r4 = 0; r4 < 4; ++r4) {
        int g = n0 + w * 16 + q * 4 + r4;
        bool ok = g < N_NODES;
        float sc = 0.f;
        if (ok) {
            float dg = (float)deg[g];
            sc = (dg > 0.f) ? __frsqrt_rn(dg) : 0.f;
        }
        #pragma unroll
        for (int nf = 0; nf < 4; ++nf) {
            if (ok) vbarh[g * 64 + nf * 16 + ln] = f2bf((acc[nf][r4] + bvb[nf]) * sc);
            psum[nf] += acc[nf][r4];
        }
    }
    #pragma unroll
    for (int nf = 0; nf < 4; ++nf) atomicAdd(&lvs[nf * 16 + ln], psum[nf]);
    __syncthreads();
    if (t < 64) atomicAdd(&vsumcol[t], lvs[t]);
}

// ---------------- GCN gather: one wave per node, lane = d-channel ----------------
// out[n,d] = aconst[d] + rsqrt(deg[n]) * sum_e w_e * vbarh[row_e, d]
__global__ __launch_bounds__(256) void k_gather(
    const int* __restrict__ off, const int* __restrict__ deg,
    const unsigned int* __restrict__ srt, const unsigned short* __restrict__ vbarh,
    const float* __restrict__ vsumcol, const float* __restrict__ bvbar,
    float* __restrict__ out)
{
    const int t = threadIdx.x;
    const int lane = t & 63;
    const int n = blockIdx.x * 4 + (t >> 6);          // grid: 12544 blocks -> 50176
    if (n >= N_NODES) return;                          // whole wave exits together
    const int e0 = off[n];
    const int dc = deg[n];
    const int e1 = e0 + dc;
    float acc = 0.f;
    int e = e0;
    for (; e + 3 < e1; e += 4) {
        unsigned int p0 = srt[e];
        unsigned int p1 = srt[e + 1];
        unsigned int p2 = srt[e + 2];
        unsigned int p3 = srt[e + 3];
        float a0 = __uint_as_float(p0 << 16) * bf2f(vbarh[(p0 >> 16) * 64 + lane]);
        float a1 = __uint_as_float(p1 << 16) * bf2f(vbarh[(p1 >> 16) * 64 + lane]);
        float a2 = __uint_as_float(p2 << 16) * bf2f(vbarh[(p2 >> 16) * 64 + lane]);
        float a3 = __uint_as_float(p3 << 16) * bf2f(vbarh[(p3 >> 16) * 64 + lane]);
        acc += (a0 + a1) + (a2 + a3);
    }
    for (; e < e1; ++e) {
        unsigned int p = srt[e];
        acc += __uint_as_float(p << 16) * bf2f(vbarh[(p >> 16) * 64 + lane]);
    }
    float dcf = (float)dc;
    float scn = (dcf > 0.f) ? __frsqrt_rn(dcf) : 0.f;
    float aconst = vsumcol[lane] * (1.0f / (float)N_NODES) + bvbar[lane];
    out[n * 64 + lane] = acc * scn + aconst;
}

extern "C" void kernel_launch(void* const* d_in, const int* in_sizes, int n_in,
                              void* d_out, int out_size, void* d_ws, size_t ws_size,
                              hipStream_t stream)
{
    const float* Xs = (const float*)d_in[1];   // source_input [N,256]
    const float* Wv = (const float*)d_in[6];   // Wv_w [256,256]
    const float* bv = (const float*)d_in[7];   // Wv_b [256]
    const int*   ei = (const int*)d_in[8];     // edge_index [2,E]
    const float* ew = (const float*)d_in[9];   // edge_weight [E]
    float* out = (float*)d_out;                // [N,64]

    unsigned short* vbarh = (unsigned short*)d_ws;               // 3.2M bf16 (6.4 MB)
    uint2* bkt  = (uint2*)(vbarh + (size_t)N_NODES * 64);        // 512*2048*8 = 8.39 MB
    unsigned int* srt = (unsigned int*)(bkt + (size_t)NBUK * BCAP); // 4.19 MB
    unsigned short* wvbar = (unsigned short*)(srt + (size_t)NBUK * BCAP); // 32 KB
    float* bvbar   = (float*)(wvbar + 16384);                    // 64
    float* vsumcol = bvbar + 64;                                 // 64
    int*   gcur    = (int*)(vsumcol + 64);                       // 512
    int*   deg     = gcur + NBUK;                                // 50,000
    int*   off     = deg + N_NODES;                              // 50,000

    // zero vsumcol + gcur (adjacent); everything else fully written by kernels
    hipMemsetAsync(vsumcol, 0, (size_t)(64 + NBUK) * 4, stream);
    k_wprep<<<16, 256, 0, stream>>>(Wv, bv, wvbar, bvbar);
    k_part<<<PBLK, 256, 0, stream>>>(ei, ew, gcur, bkt);
    k_bucket<<<NBUK, 256, 0, stream>>>(gcur, bkt, deg, off, srt);
    k_vbar<<<(N_NODES + 63) / 64, 256, 0, stream>>>(Xs, wvbar, bvbar, deg, vbarh, vsumcol);
    k_gather<<<(NBUK * BWID) / 4, 256, 0, stream>>>(off, deg, srt, vbarh, vsumcol, bvbar, out);
}